// Round 4
// baseline (637.613 us; speedup 1.0000x reference)
//
#include <hip/hip_runtime.h>

#define NPTS 294912
#define CDIM 128
#define HH 8
#define KPATCH 48
#define DD 16
#define NP (NPTS / KPATCH)      // 6144 patches
#define POS_BND 11
#define RPE_NUM 23
#define RPE_ROWS (3 * RPE_NUM)  // 69
#define QSCALE 0.25f

typedef __attribute__((ext_vector_type(8))) short short8v;  // 8 bf16
typedef __attribute__((ext_vector_type(4))) short short4v;  // 4 bf16
typedef __attribute__((ext_vector_type(4))) float f32x4;

// LDS union (36864 B):
//  Phase A (QKV GEMM):  featH [48][256B] @0 (12288) | featL @12288   (XOR (row&7)<<4)
//  Phase B (attention): Q bf16 @0 [8][48][32B], K @12288, Vt @24576 [8][16][96B]
//  Phase C (proj GEMM): aoH @0 | aoL @12288   (same layout/swizzle as feat)
#define UNI_BYTES 36864
#define KOFF 12288
#define VOFF 24576

__device__ __forceinline__ unsigned short bf16r(float x) {   // round-to-nearest-even bf16
    unsigned u = __float_as_uint(x);
    return (unsigned short)((u + 0x7fffu + ((u >> 16) & 1u)) >> 16);
}

__device__ __forceinline__ void split8(const float* x, short8v& hi, short8v& lo) {
    #pragma unroll
    for (int i = 0; i < 8; ++i) {
        unsigned u = __float_as_uint(x[i]);
        hi[i] = (short)(u >> 16);                           // truncated bf16
        float l = x[i] - __uint_as_float(u & 0xffff0000u);  // exact residual
        lo[i] = (short)(__float_as_uint(l) >> 16);
    }
}

__global__ __launch_bounds__(256, 4) void fused_patch_attn(
    const float* __restrict__ feat,
    const float* __restrict__ w_qkv,
    const float* __restrict__ b_qkv,
    const float* __restrict__ w_proj,
    const float* __restrict__ b_proj,
    const float* __restrict__ rpe,
    const int* __restrict__ order,
    const int* __restrict__ grid_coord,
    float* __restrict__ out)
{
    __shared__ int ord[KPATCH];
    __shared__ int gcl[KPATCH][3];
    __shared__ float rpe_l[RPE_ROWS * HH];
    __shared__ __align__(16) char uni[UNI_BYTES];

    const int p    = blockIdx.x;
    const int tid  = threadIdx.x;
    const int wid  = tid >> 6;
    const int lane = tid & 63;
    const int lrow = lane & 15;     // fragment row/col lane index
    const int lgrp = lane >> 4;     // k-group 0..3

    if (tid < KPATCH) {
        int o = order[p * KPATCH + tid];
        ord[tid] = o;
        gcl[tid][0] = grid_coord[o * 3 + 0];
        gcl[tid][1] = grid_coord[o * 3 + 1];
        gcl[tid][2] = grid_coord[o * 3 + 2];
    }
    for (int e = tid; e < RPE_ROWS * HH; e += 256) rpe_l[e] = rpe[e];
    __syncthreads();

    // ---- gather feat rows (48 x 128) -> bf16 hi/lo tiles (XOR-swizzled) ----
    for (int e = tid; e < KPATCH * 16; e += 256) {
        int r  = e >> 4;
        int c8 = e & 15;
        const float* src = feat + (size_t)ord[r] * CDIM + c8 * 8;
        float x[8];
        *(float4*)(x)     = *(const float4*)src;
        *(float4*)(x + 4) = *(const float4*)(src + 4);
        short8v hi, lo;
        split8(x, hi, lo);
        int addr = (r * 256 + c8 * 16) ^ ((r & 7) << 4);
        *(short8v*)(uni + addr)        = hi;
        *(short8v*)(uni + KOFF + addr) = lo;
    }
    __syncthreads();

    // ---- QKV GEMM via split-bf16 MFMA: M=48 (3 mt), N=384 (6 nt/wave), K=128 ----
    f32x4 acc[3][6];
    #pragma unroll
    for (int i = 0; i < 3; ++i)
        #pragma unroll
        for (int j = 0; j < 6; ++j) acc[i][j] = (f32x4)0.0f;

    #pragma unroll
    for (int ks = 0; ks < 4; ++ks) {
        short8v aH[3], aL[3];
        #pragma unroll
        for (int mt = 0; mt < 3; ++mt) {
            int row  = mt * 16 + lrow;
            int boff = (row * 256 + ks * 64 + lgrp * 16) ^ ((row & 7) << 4);
            aH[mt] = *(const short8v*)(uni + boff);
            aL[mt] = *(const short8v*)(uni + KOFF + boff);
        }
        #pragma unroll
        for (int nt = 0; nt < 6; ++nt) {
            int NT = wid * 6 + nt;
            const float* wp = w_qkv + (size_t)(NT * 16 + lrow) * CDIM + ks * 32 + lgrp * 8;
            float x[8];
            *(float4*)(x)     = *(const float4*)wp;
            *(float4*)(x + 4) = *(const float4*)(wp + 4);
            short8v bH, bL;
            split8(x, bH, bL);
            #pragma unroll
            for (int mt = 0; mt < 3; ++mt) {
                acc[mt][nt] = __builtin_amdgcn_mfma_f32_16x16x32_bf16(aH[mt], bH, acc[mt][nt], 0, 0, 0);
                acc[mt][nt] = __builtin_amdgcn_mfma_f32_16x16x32_bf16(aL[mt], bH, acc[mt][nt], 0, 0, 0);
                acc[mt][nt] = __builtin_amdgcn_mfma_f32_16x16x32_bf16(aH[mt], bL, acc[mt][nt], 0, 0, 0);
            }
        }
    }
    __syncthreads();   // feat tile reads done; region becomes Q/K/Vt bf16

    // ---- write qkv accumulators (+bias, q*scale) as bf16 into Q/K/Vt ----
    // Q/K: [h][m][32B row], d-group unit 8B swizzled by XOR with (m>>2)&3
    // Vt:  [h][d][96B row], m-group unit 8B swizzled by XOR with (d>>2)&3
    #pragma unroll
    for (int nt = 0; nt < 6; ++nt) {
        int NT   = wid * 6 + nt;
        int type = NT >> 3;          // 0=q 1=k 2=v (uniform per wave-tile)
        int hh   = NT & 7;
        int d    = lrow;
        float bq = b_qkv[NT * 16 + lrow];
        float scale = (type == 0) ? QSCALE : 1.0f;
        #pragma unroll
        for (int mt = 0; mt < 3; ++mt)
            #pragma unroll
            for (int r = 0; r < 4; ++r) {
                int m = mt * 16 + lgrp * 4 + r;
                unsigned short b = bf16r((acc[mt][nt][r] + bq) * scale);
                int addr;
                if (type < 2) {
                    addr = type * KOFF + hh * 1536 + m * 32
                         + (((d >> 2) ^ (m >> 2)) & 3) * 8 + (d & 3) * 2;
                } else {
                    int mb = m >> 2;
                    addr = VOFF + hh * 1536 + d * 96
                         + (((mb & ~3) | ((mb ^ (d >> 2)) & 3))) * 8 + (m & 3) * 2;
                }
                *(unsigned short*)(uni + addr) = b;
            }
    }
    __syncthreads();

    // ---- MFMA attention: 2 heads per wave ----
    f32x4 oall[2][3];
    #pragma unroll
    for (int ht = 0; ht < 2; ++ht) {
        const int h = wid * 2 + ht;
        // K A-frags (rows m) and Q B-frags (cols q): k-slots 0-3 = d (lgrp*4+j), 4-7 = zero pad
        short8v kf[3], qf[3];
        #pragma unroll
        for (int t = 0; t < 3; ++t) {
            int row = t * 16 + lrow;
            int ra  = row * 32 + (((lgrp ^ (row >> 2)) & 3)) * 8;
            short4v kq = *(const short4v*)(uni + KOFF + h * 1536 + ra);
            short4v qq = *(const short4v*)(uni +        h * 1536 + ra);
            short8v a, b;
            a[0]=kq[0]; a[1]=kq[1]; a[2]=kq[2]; a[3]=kq[3]; a[4]=0; a[5]=0; a[6]=0; a[7]=0;
            b[0]=qq[0]; b[1]=qq[1]; b[2]=qq[2]; b[3]=qq[3]; b[4]=0; b[5]=0; b[6]=0; b[7]=0;
            kf[t] = a; qf[t] = b;
        }
        // S[m][q] tiles: C row = m local (lgrp*4+r), col = q local (lrow)
        f32x4 s[3][3];
        #pragma unroll
        for (int qt = 0; qt < 3; ++qt)
            #pragma unroll
            for (int mt = 0; mt < 3; ++mt)
                s[qt][mt] = __builtin_amdgcn_mfma_f32_16x16x32_bf16(kf[mt], qf[qt], (f32x4)0.0f, 0, 0, 0);

        // relative-position bias
        #pragma unroll
        for (int qt = 0; qt < 3; ++qt) {
            int q  = qt * 16 + lrow;
            int gx = gcl[q][0], gy = gcl[q][1], gz = gcl[q][2];
            #pragma unroll
            for (int mt = 0; mt < 3; ++mt)
                #pragma unroll
                for (int r = 0; r < 4; ++r) {
                    int m  = mt * 16 + lgrp * 4 + r;
                    int rx = gx - gcl[m][0];
                    int ry = gy - gcl[m][1];
                    int rz = gz - gcl[m][2];
                    rx = rx < -POS_BND ? -POS_BND : (rx > POS_BND ? POS_BND : rx);
                    ry = ry < -POS_BND ? -POS_BND : (ry > POS_BND ? POS_BND : ry);
                    rz = rz < -POS_BND ? -POS_BND : (rz > POS_BND ? POS_BND : rz);
                    s[qt][mt][r] += rpe_l[(rx + POS_BND) * HH + h]
                                  + rpe_l[(ry + POS_BND + RPE_NUM) * HH + h]
                                  + rpe_l[(rz + POS_BND + 2 * RPE_NUM) * HH + h];
                }
        }

        // softmax over m (12 local + cross-lane over row-groups: lanes l^16, l^32)
        #pragma unroll
        for (int qt = 0; qt < 3; ++qt) {
            float mx = -1e30f;
            #pragma unroll
            for (int mt = 0; mt < 3; ++mt)
                #pragma unroll
                for (int r = 0; r < 4; ++r) mx = fmaxf(mx, s[qt][mt][r]);
            mx = fmaxf(mx, __shfl_xor(mx, 16));
            mx = fmaxf(mx, __shfl_xor(mx, 32));
            float sum = 0.f;
            #pragma unroll
            for (int mt = 0; mt < 3; ++mt)
                #pragma unroll
                for (int r = 0; r < 4; ++r) {
                    float e = __expf(s[qt][mt][r] - mx);
                    s[qt][mt][r] = e;
                    sum += e;
                }
            sum += __shfl_xor(sum, 16);
            sum += __shfl_xor(sum, 32);
            float inv = 1.0f / sum;
            #pragma unroll
            for (int mt = 0; mt < 3; ++mt)
                #pragma unroll
                for (int r = 0; r < 4; ++r) s[qt][mt][r] *= inv;
        }

        // V B-frags: custom k-slot map {j0-3: m=ms*32+lgrp*4+j, j4-7: +16} matching P regs
        short8v vb0, vb1;
        {
            int base = VOFF + h * 1536 + lrow * 96 + (((lgrp ^ (lrow >> 2)) & 3)) * 8;
            short4v x0 = *(const short4v*)(uni + base);        // m 0..15 group
            short4v x1 = *(const short4v*)(uni + base + 32);   // m 16..31 group
            short4v x2 = *(const short4v*)(uni + base + 64);   // m 32..47 group
            vb0[0]=x0[0]; vb0[1]=x0[1]; vb0[2]=x0[2]; vb0[3]=x0[3];
            vb0[4]=x1[0]; vb0[5]=x1[1]; vb0[6]=x1[2]; vb0[7]=x1[3];
            vb1[0]=x2[0]; vb1[1]=x2[1]; vb1[2]=x2[2]; vb1[3]=x2[3];
            vb1[4]=0; vb1[5]=0; vb1[6]=0; vb1[7]=0;
        }
        // PV: out[q][d] per qt; P regs are already A-fragments under the same k-slot map
        #pragma unroll
        for (int qt = 0; qt < 3; ++qt) {
            short8v pa0, pa1;
            #pragma unroll
            for (int j = 0; j < 4; ++j) {
                pa0[j]     = (short)bf16r(s[qt][0][j]);
                pa0[4 + j] = (short)bf16r(s[qt][1][j]);
                pa1[j]     = (short)bf16r(s[qt][2][j]);
                pa1[4 + j] = 0;
            }
            f32x4 o = __builtin_amdgcn_mfma_f32_16x16x32_bf16(pa0, vb0, (f32x4)0.0f, 0, 0, 0);
            o = __builtin_amdgcn_mfma_f32_16x16x32_bf16(pa1, vb1, o, 0, 0, 0);
            oall[ht][qt] = o;
        }
    }
    __syncthreads();   // all qkv reads done; region becomes aoH/aoL

    // ---- write attention output hi/lo bf16 tile (same layout/swizzle as feat) ----
    #pragma unroll
    for (int ht = 0; ht < 2; ++ht) {
        int c = (wid * 2 + ht) * 16 + lrow;     // output column = h*16 + d
        #pragma unroll
        for (int qt = 0; qt < 3; ++qt)
            #pragma unroll
            for (int r = 0; r < 4; ++r) {
                int q = qt * 16 + lgrp * 4 + r; // output row
                float x = oall[ht][qt][r];
                unsigned u = __float_as_uint(x);
                unsigned short h16 = (unsigned short)(u >> 16);
                float lres = x - __uint_as_float(u & 0xffff0000u);
                unsigned short l16 = (unsigned short)(__float_as_uint(lres) >> 16);
                int addr = (q * 256 + c * 2) ^ ((q & 7) << 4);
                *(unsigned short*)(uni + addr)        = h16;
                *(unsigned short*)(uni + KOFF + addr) = l16;
            }
    }
    __syncthreads();

    // ---- proj GEMM via split-bf16 MFMA: M=48, N=128 (2 nt/wave), K=128 ----
    f32x4 pacc[3][2];
    #pragma unroll
    for (int i = 0; i < 3; ++i)
        #pragma unroll
        for (int j = 0; j < 2; ++j) pacc[i][j] = (f32x4)0.0f;

    #pragma unroll
    for (int ks = 0; ks < 4; ++ks) {
        short8v aH[3], aL[3];
        #pragma unroll
        for (int mt = 0; mt < 3; ++mt) {
            int row  = mt * 16 + lrow;
            int boff = (row * 256 + ks * 64 + lgrp * 16) ^ ((row & 7) << 4);
            aH[mt] = *(const short8v*)(uni + boff);
            aL[mt] = *(const short8v*)(uni + KOFF + boff);
        }
        #pragma unroll
        for (int nt = 0; nt < 2; ++nt) {
            int NT = wid * 2 + nt;
            const float* wp = w_proj + (size_t)(NT * 16 + lrow) * CDIM + ks * 32 + lgrp * 8;
            float x[8];
            *(float4*)(x)     = *(const float4*)wp;
            *(float4*)(x + 4) = *(const float4*)(wp + 4);
            short8v bH, bL;
            split8(x, bH, bL);
            #pragma unroll
            for (int mt = 0; mt < 3; ++mt) {
                pacc[mt][nt] = __builtin_amdgcn_mfma_f32_16x16x32_bf16(aH[mt], bH, pacc[mt][nt], 0, 0, 0);
                pacc[mt][nt] = __builtin_amdgcn_mfma_f32_16x16x32_bf16(aL[mt], bH, pacc[mt][nt], 0, 0, 0);
                pacc[mt][nt] = __builtin_amdgcn_mfma_f32_16x16x32_bf16(aH[mt], bL, pacc[mt][nt], 0, 0, 0);
            }
        }
    }

    // ---- scatter rows to out (+bias) ----
    #pragma unroll
    for (int nt = 0; nt < 2; ++nt) {
        int NT = wid * 2 + nt;
        int c  = NT * 16 + lrow;
        float bp = b_proj[c];
        #pragma unroll
        for (int mt = 0; mt < 3; ++mt)
            #pragma unroll
            for (int r = 0; r < 4; ++r) {
                int row = mt * 16 + lgrp * 4 + r;
                out[(size_t)ord[row] * CDIM + c] = pacc[mt][nt][r] + bp;
            }
    }
}

extern "C" void kernel_launch(void* const* d_in, const int* in_sizes, int n_in,
                              void* d_out, int out_size, void* d_ws, size_t ws_size,
                              hipStream_t stream) {
    const float* feat   = (const float*)d_in[0];
    const float* w_qkv  = (const float*)d_in[1];
    const float* b_qkv  = (const float*)d_in[2];
    const float* w_proj = (const float*)d_in[3];
    const float* b_proj = (const float*)d_in[4];
    const float* rpe    = (const float*)d_in[5];
    const int*   order  = (const int*)d_in[6];
    const int*   gc     = (const int*)d_in[8];
    float* out = (float*)d_out;

    fused_patch_attn<<<NP, 256, 0, stream>>>(feat, w_qkv, b_qkv, w_proj, b_proj,
                                             rpe, order, gc, out);
}